// Round 5
// baseline (343.738 us; speedup 1.0000x reference)
//
#include <hip/hip_runtime.h>
#include <math.h>

#define N_    200
#define B_    512
#define K1_   100
#define K2_   50
#define ST    36     // sH row stride (dwords): 144B, 16B-aligned
#define XS    21     // x-stage row stride (dwords): gcd(21,32)=1 -> conflict-free per-lane-row reads
#define KT    20     // k-tile width (200 = 10 * 20, uniform tiles)
#define NT    10

// out layout: logp [512*2] | s1 [512*100] | s2 [512*50]
#define S1_OFF 1024
#define S2_OFF 52224

__device__ __forceinline__ float lrelu(float v) { return v > 0.f ? v : 0.2f * v; }
__device__ __forceinline__ float sigm(float v)  { return 1.f / (1.f + __expf(-v)); }

// LDS overlay map (bytes), total 72768 (2 blocks/CU; grid-capped at 2 anyway):
//     0 : x dbuf 33600  [2][200*21] f32, phase A only; after A: sW2 @0 (4096), sMask2 @4096 (2000)
// 33600 : sH    28800  h(200xST) A-B; h1 in-place B-C; rows 100..199 = sXK (C-F);
//                      rows 0..99: h2a then h2 in-place (E-F)
// 62400 : sBITS  6400  adj>0 bitmask, 8 u32/row (ballot-built), lives A-D
// 68800 : sES     800
// 69600 : sED     800
// 70400 : sKey   1024
// 71424 : sSel    400
// 71824 : sVal    400
// 72224 : sXV     512
// 72736 : sRed     32

__global__ __launch_bounds__(256) void gnn_fused(
    const float* __restrict__ x, const float* __restrict__ adj,
    const float* __restrict__ W1, const float* __restrict__ a1s,
    const float* __restrict__ a1d, const float* __restrict__ b1,
    const float* __restrict__ W2g, const float* __restrict__ a2s,
    const float* __restrict__ a2d, const float* __restrict__ b2,
    const float* __restrict__ pw1, const float* __restrict__ pw2,
    const float* __restrict__ fc1w, const float* __restrict__ fc1b,
    const float* __restrict__ fc2w, const float* __restrict__ fc2b,
    const float* __restrict__ fc3w, const float* __restrict__ fc3b,
    const float* __restrict__ bn4g, const float* __restrict__ bn4b,
    const float* __restrict__ bn5g, const float* __restrict__ bn5b,
    float* __restrict__ out)
{
  __shared__ __align__(16) char smem[72768];
  float*    sXs   = (float*)smem;                  // [2][4200] dwords
  float*    sW2   = (float*)smem;                  // alias, after phase A
  unsigned* sMask2= (unsigned*)(smem + 4096);      // alias, after phase A
  float*    sH    = (float*)(smem + 33600);
  float*    sXK   = sH + 100 * ST;                 // rows 100..199 of sH
  unsigned* sBITS = (unsigned*)(smem + 62400);
  float*    sES   = (float*)(smem + 68800);
  float*    sED   = (float*)(smem + 69600);
  float*    sKey  = (float*)(smem + 70400);
  int*      sSel  = (int*)(smem + 71424);
  float*    sVal  = (float*)(smem + 71824);
  float*    sXV   = (float*)(smem + 72224);
  float*    sRed  = (float*)(smem + 72736);

  const int t  = threadIdx.x;
  const int b  = blockIdx.x;
  const int wv = t >> 6, ln = t & 63;
  const float* xb = x   + (size_t)b * N_ * N_;
  const float* ab = adj + (size_t)b * N_ * N_;
  const float4* xb4 = (const float4*)xb;

  // ---------------- Phase A: h = x @ W1 (k-tiled, double-buffered LDS staging) ----------------
  // fill mapping per tile: 1000 float4 (200 rows x 5 float4); f = t + i*256; r=f/5, c=f%5.
  // global float4 index = r*50 + kb/4 + c  (row-major, kb = tile*KT, KT%4==0)
  float acc[32];
  #pragma unroll
  for (int d = 0; d < 32; ++d) acc[d] = 0.f;

  float4 q0, q1, q2, q3;
  {
    int f0 = t,        r0 = f0 / 5, c0 = f0 % 5;
    int f1 = t + 256,  r1 = f1 / 5, c1 = f1 % 5;
    int f2 = t + 512,  r2 = f2 / 5, c2 = f2 % 5;
    int f3 = t + 768,  r3 = f3 / 5, c3 = f3 % 5;
    q0 = xb4[r0 * 50 + c0];
    q1 = xb4[r1 * 50 + c1];
    q2 = xb4[r2 * 50 + c2];
    if (f3 < 1000) q3 = xb4[r3 * 50 + c3];
    // write tile 0 into buf 0
    float* d0 = sXs + r0 * XS + c0 * 4; d0[0]=q0.x; d0[1]=q0.y; d0[2]=q0.z; d0[3]=q0.w;
    float* d1 = sXs + r1 * XS + c1 * 4; d1[0]=q1.x; d1[1]=q1.y; d1[2]=q1.z; d1[3]=q1.w;
    float* d2 = sXs + r2 * XS + c2 * 4; d2[0]=q2.x; d2[1]=q2.y; d2[2]=q2.z; d2[3]=q2.w;
    if (f3 < 1000) { float* d3 = sXs + r3 * XS + c3 * 4; d3[0]=q3.x; d3[1]=q3.y; d3[2]=q3.z; d3[3]=q3.w; }
  }
  __syncthreads();

  int cur = 0;
  for (int it = 0; it < NT; ++it) {
    // issue next-tile global loads (latency hides under this tile's compute)
    if (it + 1 < NT) {
      int kb4 = (it + 1) * (KT / 4);
      int f0 = t,       r0 = f0 / 5, c0 = f0 % 5;
      int f1 = t + 256, r1 = f1 / 5, c1 = f1 % 5;
      int f2 = t + 512, r2 = f2 / 5, c2 = f2 % 5;
      int f3 = t + 768, r3 = f3 / 5, c3 = f3 % 5;
      q0 = xb4[r0 * 50 + kb4 + c0];
      q1 = xb4[r1 * 50 + kb4 + c1];
      q2 = xb4[r2 * 50 + kb4 + c2];
      if (f3 < 1000) q3 = xb4[r3 * 50 + kb4 + c3];
    }
    // cooperative adj ballot-scan: 5 rows per wave per tile (coalesced; bits built by ballot)
    {
      int rbase = wv * 50 + it * 5;
      for (int rr = 0; rr < 5; ++rr) {
        int row = rbase + rr;
        const float* arow = ab + row * N_;
        float a0 = arow[ln];
        float a1 = arow[64 + ln];
        float a2 = arow[128 + ln];
        float a3 = (ln < 8) ? arow[192 + ln] : -1.f;
        unsigned long long b0 = __ballot(a0 > 0.f);
        unsigned long long b1 = __ballot(a1 > 0.f);
        unsigned long long b2 = __ballot(a2 > 0.f);
        unsigned long long b3 = __ballot(a3 > 0.f);
        if (ln == 0) {
          sBITS[row * 8 + 0] = (unsigned)b0; sBITS[row * 8 + 1] = (unsigned)(b0 >> 32);
          sBITS[row * 8 + 2] = (unsigned)b1; sBITS[row * 8 + 3] = (unsigned)(b1 >> 32);
          sBITS[row * 8 + 4] = (unsigned)b2; sBITS[row * 8 + 5] = (unsigned)(b2 >> 32);
          sBITS[row * 8 + 6] = (unsigned)b3;
        }
      }
    }
    // compute this tile from LDS (conflict-free: bank = (21*t + k) % 32, gcd(21,32)=1)
    if (t < N_) {
      const float* xr = sXs + cur * 4200 + t * XS;
      const int k0 = it * KT;
      for (int k = 0; k < KT; k += 4) {
        float x0 = xr[k], x1 = xr[k + 1], x2 = xr[k + 2], x3 = xr[k + 3];
        const float* w0 = W1 + (k0 + k) * 32;       // uniform -> scalar loads
        const float* w1 = w0 + 32;
        const float* w2 = w0 + 64;
        const float* w3 = w0 + 96;
        #pragma unroll
        for (int d = 0; d < 32; ++d) acc[d] += x0 * w0[d];
        #pragma unroll
        for (int d = 0; d < 32; ++d) acc[d] += x1 * w1[d];
        #pragma unroll
        for (int d = 0; d < 32; ++d) acc[d] += x2 * w2[d];
        #pragma unroll
        for (int d = 0; d < 32; ++d) acc[d] += x3 * w3[d];
      }
    }
    __syncthreads();                 // reads of buf (cur^1 writers wait) done
    if (it + 1 < NT) {
      float* B = sXs + (cur ^ 1) * 4200;
      int f0 = t,       r0 = f0 / 5, c0 = f0 % 5;
      int f1 = t + 256, r1 = f1 / 5, c1 = f1 % 5;
      int f2 = t + 512, r2 = f2 / 5, c2 = f2 % 5;
      int f3 = t + 768, r3 = f3 / 5, c3 = f3 % 5;
      float* d0 = B + r0 * XS + c0 * 4; d0[0]=q0.x; d0[1]=q0.y; d0[2]=q0.z; d0[3]=q0.w;
      float* d1 = B + r1 * XS + c1 * 4; d1[0]=q1.x; d1[1]=q1.y; d1[2]=q1.z; d1[3]=q1.w;
      float* d2 = B + r2 * XS + c2 * 4; d2[0]=q2.x; d2[1]=q2.y; d2[2]=q2.z; d2[3]=q2.w;
      if (f3 < 1000) { float* d3 = B + r3 * XS + c3 * 4; d3[0]=q3.x; d3[1]=q3.y; d3[2]=q3.z; d3[3]=q3.w; }
      __syncthreads();               // new tile visible
    }
    cur ^= 1;
  }

  // es/ed + h write
  if (t < N_) {
    float es = 0.f, ed = 0.f;
    #pragma unroll
    for (int d = 0; d < 32; ++d) { es += acc[d] * a1s[d]; ed += acc[d] * a1d[d]; }
    sES[t] = es; sED[t] = ed;
    #pragma unroll
    for (int d = 0; d < 32; ++d) sH[t * ST + d] = acc[d];
  }
  __syncthreads();

  // W2 fill (x-buffer region dead now; overlaps esmax + phase B) + esmax reduce
  for (int i = t; i < 1024; i += 256) sW2[i] = W2g[i];
  {
    float v = (t < N_) ? sES[t] : -3.0e38f;
    #pragma unroll
    for (int off = 1; off < 64; off <<= 1) v = fmaxf(v, __shfl_xor(v, off, 64));
    if ((t & 63) == 0) sRed[t >> 6] = v;
  }
  __syncthreads();
  {
    float esmax = fmaxf(fmaxf(sRed[0], sRed[1]), fmaxf(sRed[2], sRed[3]));

    // -------------- Phase B: sparse masked-softmax aggregate from bit masks (no global) --------------
    if (t < N_) {
      unsigned long long m0 = (unsigned long long)sBITS[t * 8 + 0] | ((unsigned long long)sBITS[t * 8 + 1] << 32);
      unsigned long long m1 = (unsigned long long)sBITS[t * 8 + 2] | ((unsigned long long)sBITS[t * 8 + 3] << 32);
      unsigned long long m2 = (unsigned long long)sBITS[t * 8 + 4] | ((unsigned long long)sBITS[t * 8 + 5] << 32);
      unsigned long long m3 = (unsigned long long)sBITS[t * 8 + 6];
      if (t < 64)       m0 |= 1ull << t;
      else if (t < 128) m1 |= 1ull << (t - 64);
      else if (t < 192) m2 |= 1ull << (t - 128);
      else              m3 |= 1ull << (t - 192);
      float ed_i = sED[t];
      float L = lrelu(ed_i + esmax);
      float ssum = 0.f;
      #pragma unroll
      for (int d = 0; d < 32; ++d) acc[d] = 0.f;
      #define AGG(mm, base)                                                        \
        while (mm) {                                                               \
          int j = (base) + (int)__builtin_ctzll(mm); mm &= (mm - 1);               \
          float w = __expf(lrelu(ed_i + sES[j]) - L); ssum += w;                   \
          const float* hr = &sH[j * ST];                                           \
          _Pragma("unroll")                                                        \
          for (int c = 0; c < 8; ++c) {                                            \
            float4 hv = *(const float4*)(hr + c * 4);                              \
            acc[c*4+0] += w * hv.x; acc[c*4+1] += w * hv.y;                        \
            acc[c*4+2] += w * hv.z; acc[c*4+3] += w * hv.w;                        \
          }                                                                        \
        }
      AGG(m0, 0) AGG(m1, 64) AGG(m2, 128) AGG(m3, 192)
      #undef AGG
      float inv = 1.f / ssum;
      #pragma unroll
      for (int d = 0; d < 32; ++d) acc[d] = acc[d] * inv + b1[d];
    }
    __syncthreads();                 // all reads of h done -> overwrite with h1
    if (t < N_) {
      #pragma unroll
      for (int d = 0; d < 32; ++d) sH[t * ST + d] = acc[d];
    }
  }
  __syncthreads();

  // -------------- Phase C: TopK pool 1 via barrier-free rank-select --------------
  {
    float npw = 0.f;
    #pragma unroll
    for (int d = 0; d < 32; ++d) npw += pw1[d] * pw1[d];
    npw = sqrtf(npw) + 1e-16f;
    float sc = -1.f;
    if (t < N_) {
      float dp = 0.f;
      #pragma unroll
      for (int d = 0; d < 32; ++d) dp += sH[t * ST + d] * pw1[d];
      sc = sigm(dp / npw);
    }
    sKey[t] = sc;
  }
  __syncthreads();
  if (t < N_) {
    float sc = sKey[t];
    int rank = 0;
    for (int j = 0; j < N_; j += 4) {
      #pragma unroll
      for (int jj = 0; jj < 4; ++jj) {
        float o = sKey[j + jj];                       // uniform -> broadcast
        rank += (o > sc || (o == sc && (j + jj) < t)) ? 1 : 0;
      }
    }
    if (rank < K1_) {                                 // stable desc order == lax.top_k
      sSel[rank] = t; sVal[rank] = sc;
      out[S1_OFF + b * K1_ + rank] = sc;
    }
  }
  __syncthreads();
  // xk = h1[sel]*val. Dest (sH rows 100..199) aliases source rows -> reg staging.
  {
    float tmp[13];
    #pragma unroll
    for (int it = 0; it < 13; ++it) {
      int i = t + it * 256;
      if (i < K1_ * 32) tmp[it] = sH[sSel[i >> 5] * ST + (i & 31)] * sVal[i >> 5];
    }
    __syncthreads();
    #pragma unroll
    for (int it = 0; it < 13; ++it) {
      int i = t + it * 256;
      if (i < K1_ * 32) sXK[(i >> 5) * ST + (i & 31)] = tmp[it];
    }
  }
  __syncthreads();
  // x1 = [max, mean] over 100 pooled nodes
  if (t < 32) {
    float m = -3.0e38f, s = 0.f;
    for (int r = 0; r < K1_; ++r) { float v = sXK[r * ST + t]; m = fmaxf(m, v); s += v; }
    sXV[t] = m; sXV[32 + t] = s / 100.f;
  }

  // -------------- Phase D: 2-hop mask (a2 != 0 | eye), boolean bitsets --------------
  if (t < K1_) {
    int gi = sSel[t];
    #pragma unroll
    for (int w = 0; w < 4; ++w) {
      unsigned m = 0;
      const int lim = (w < 3) ? 32 : 4;
      for (int jj = 0; jj < lim; ++jj) {
        int j = w * 32 + jj;
        int gj = sSel[j];
        unsigned bit = (sBITS[gi * 8 + (gj >> 5)] >> (gj & 31)) & 1u;
        if (j == t) bit = 1u;                       // (A+I) self loop
        m |= bit << jj;
      }
      sMask2[t * 5 + w] = m;
    }
  }
  __syncthreads();
  {
    unsigned pr0 = 0, pr1 = 0, pr2 = 0, pr3 = 0;
    if (t < K1_) {
      #pragma unroll
      for (int kw = 0; kw < 4; ++kw) {
        unsigned mk = sMask2[t * 5 + kw];
        const int lim = (kw < 3) ? 32 : 4;
        for (int kk = 0; kk < lim; ++kk) {
          if ((mk >> kk) & 1u) {
            int k = kw * 32 + kk;
            pr0 |= sMask2[k * 5 + 0]; pr1 |= sMask2[k * 5 + 1];
            pr2 |= sMask2[k * 5 + 2]; pr3 |= sMask2[k * 5 + 3];
          }
        }
      }
    }
    __syncthreads();
    if (t < K1_) {
      sMask2[t * 5 + 0] = pr0; sMask2[t * 5 + 1] = pr1;
      sMask2[t * 5 + 2] = pr2; sMask2[t * 5 + 3] = pr3;
    }
  }
  __syncthreads();

  // -------------- Phase E: GAT2 --------------
  // h2a = xk @ W2 -> sH rows 0..99 (h1 rows 0..99 dead; xk rows 100..199 untouched)
  if (t < K1_) {
    float xk[32];
    #pragma unroll
    for (int c = 0; c < 8; ++c) *(float4*)&xk[c * 4] = *(const float4*)&sXK[t * ST + c * 4];
    float acc2[32];
    #pragma unroll
    for (int d = 0; d < 32; ++d) acc2[d] = 0.f;
    #pragma unroll
    for (int k = 0; k < 32; ++k) {
      float xv = xk[k];
      const float* wr = &sW2[k * 32];
      #pragma unroll
      for (int d = 0; d < 32; ++d) acc2[d] += xv * wr[d];
    }
    float es = 0.f, ed = 0.f;
    #pragma unroll
    for (int d = 0; d < 32; ++d) { es += acc2[d] * a2s[d]; ed += acc2[d] * a2d[d]; }
    sES[t] = es; sED[t] = ed;
    #pragma unroll
    for (int d = 0; d < 32; ++d) sH[t * ST + d] = acc2[d];
  }
  __syncthreads();
  {
    float v = (t < K1_) ? sES[t] : -3.0e38f;
    #pragma unroll
    for (int off = 1; off < 64; off <<= 1) v = fmaxf(v, __shfl_xor(v, off, 64));
    if ((t & 63) == 0) sRed[t >> 6] = v;
  }
  __syncthreads();
  {
    float esm2 = fmaxf(fmaxf(sRed[0], sRed[1]), fmaxf(sRed[2], sRed[3]));
    float acc2[32];
    if (t < K1_) {
      float ed_i = sED[t];
      float L = lrelu(ed_i + esm2);
      float ssum = 0.f;
      #pragma unroll
      for (int d = 0; d < 32; ++d) acc2[d] = 0.f;
      #pragma unroll
      for (int jw = 0; jw < 4; ++jw) {
        unsigned mw = sMask2[t * 5 + jw];
        const int lim = (jw < 3) ? 32 : 4;
        for (int jj = 0; jj < lim; ++jj) {
          int j = jw * 32 + jj;
          float w = 0.f;
          if ((mw >> jj) & 1u) w = __expf(lrelu(ed_i + sES[j]) - L);
          ssum += w;
          const float* hr = &sH[j * ST];          // uniform -> broadcast
          #pragma unroll
          for (int d = 0; d < 32; ++d) acc2[d] += w * hr[d];
        }
      }
      float inv = 1.f / ssum;
      #pragma unroll
      for (int d = 0; d < 32; ++d) acc2[d] = acc2[d] * inv + b2[d];
    }
    __syncthreads();               // all reads of h2a done -> overwrite with h2
    if (t < K1_) {
      #pragma unroll
      for (int d = 0; d < 32; ++d) sH[t * ST + d] = acc2[d];
    }
  }
  __syncthreads();

  // -------------- Phase F: TopK pool 2 via rank-select --------------
  {
    float npw = 0.f;
    #pragma unroll
    for (int d = 0; d < 32; ++d) npw += pw2[d] * pw2[d];
    npw = sqrtf(npw) + 1e-16f;
    if (t < K1_) {
      float dp = 0.f;
      #pragma unroll
      for (int d = 0; d < 32; ++d) dp += sH[t * ST + d] * pw2[d];
      sKey[t] = sigm(dp / npw);
    }
  }
  __syncthreads();
  if (t < K1_) {
    float sc = sKey[t];
    int rank = 0;
    for (int j = 0; j < K1_; j += 4) {
      #pragma unroll
      for (int jj = 0; jj < 4; ++jj) {
        float o = sKey[j + jj];
        rank += (o > sc || (o == sc && (j + jj) < t)) ? 1 : 0;
      }
    }
    if (rank < K2_) {
      sSel[rank] = t; sVal[rank] = sc;
      out[S2_OFF + b * K2_ + rank] = sc;
    }
  }
  __syncthreads();
  {  // xk2: reads h2 (sH rows 0..99), writes sXK rows 0..49 (sH rows 100..149) - disjoint
    int d = t & 31, r0 = t >> 5;
    for (int r = r0; r < K2_; r += 8) sXK[r * ST + d] = sH[sSel[r] * ST + d] * sVal[r];
  }
  __syncthreads();
  if (t < 32) {
    float m = -3.0e38f, s = 0.f;
    for (int r = 0; r < K2_; ++r) { float v = sXK[r * ST + t]; m = fmaxf(m, v); s += v; }
    sXV[64 + t] = m; sXV[96 + t] = s / 50.f;
  }
  __syncthreads();

  // -------------- Phase G: MLP head --------------
  const float RS = 0.99999500003749969f;   // 1/sqrt(1+1e-5)
  if (t < 32) {
    float z = fc1b[t];
    for (int k = 0; k < 128; ++k) z += sXV[k] * fc1w[k * 32 + t];
    z = fmaxf(z, 0.f);
    z = bn4g[t] * z * RS + bn4b[t];
    sKey[t] = z;
  }
  __syncthreads();
  if (t < 8) {
    float z = fc2b[t];
    for (int k = 0; k < 32; ++k) z += sKey[k] * fc2w[k * 8 + t];
    z = fmaxf(z, 0.f);
    z = bn5g[t] * z * RS + bn5b[t];
    sKey[32 + t] = z;
  }
  __syncthreads();
  if (t < 2) {
    float z = fc3b[t];
    for (int k = 0; k < 8; ++k) z += sKey[32 + k] * fc3w[k * 2 + t];
    sKey[40 + t] = z;
  }
  __syncthreads();
  if (t < 2) {
    float z0 = sKey[40], z1 = sKey[41];
    float m = fmaxf(z0, z1);
    float lse = m + logf(__expf(z0 - m) + __expf(z1 - m));
    out[b * 2 + t] = sKey[40 + t] - lse;
  }
}

extern "C" void kernel_launch(void* const* d_in, const int* in_sizes, int n_in,
                              void* d_out, int out_size, void* d_ws, size_t ws_size,
                              hipStream_t stream) {
  (void)in_sizes; (void)n_in; (void)d_ws; (void)ws_size; (void)out_size;
  const float* x    = (const float*)d_in[0];
  const float* adj  = (const float*)d_in[1];
  const float* W1   = (const float*)d_in[2];
  const float* a1s  = (const float*)d_in[3];
  const float* a1d  = (const float*)d_in[4];
  const float* b1   = (const float*)d_in[5];
  const float* W2   = (const float*)d_in[6];
  const float* a2s  = (const float*)d_in[7];
  const float* a2d  = (const float*)d_in[8];
  const float* b2   = (const float*)d_in[9];
  const float* pw1  = (const float*)d_in[10];
  const float* pw2  = (const float*)d_in[11];
  const float* fc1w = (const float*)d_in[12];
  const float* fc1b = (const float*)d_in[13];
  const float* fc2w = (const float*)d_in[14];
  const float* fc2b = (const float*)d_in[15];
  const float* fc3w = (const float*)d_in[16];
  const float* fc3b = (const float*)d_in[17];
  const float* bn4g = (const float*)d_in[18];
  const float* bn4b = (const float*)d_in[19];
  const float* bn5g = (const float*)d_in[20];
  const float* bn5b = (const float*)d_in[21];

  gnn_fused<<<B_, 256, 0, stream>>>(x, adj, W1, a1s, a1d, b1, W2, a2s, a2d, b2,
                                    pw1, pw2, fc1w, fc1b, fc2w, fc2b, fc3w, fc3b,
                                    bn4g, bn4b, bn5g, bn5b, (float*)d_out);
}